// Round 8
// baseline (486.450 us; speedup 1.0000x reference)
//
#include <hip/hip_runtime.h>

// GCN encoder: 3x GCNConv (sym-norm, self-loops) + 2x BatchNorm(train)+ReLU+residual.
// N=50000, E=800000, IN=HID=128, OUT=64. fp32 in/out; edge_index int32.
//
// R2: CSR gather.  R3: reg-tiled GEMMs.  R4: hier. scan.  R5: xs bf16.
// R6: MFMA bf16 GEMMs.  R7: 2-level counting-sort CSR build.
// R8: BN-stats fused into gather (register Sigma/Sigma^2 + LDS reduce, k_stats gone);
//     BN+ReLU+residual fused into MFMA GEMM A-fragment build (bnrelu + xb
//     round-trip gone); gather unroll-4. Gather FETCH (~113MB) is near the
//     compulsory floor: 8 XCD private L2s x 12.8MB xs ~= 102MB minimum fill.
// BN bias-cancel: b1/b2 vanish inside BatchNorm; only b3 applied.
// NOTE: N must be < 65536 for the u16 packing in k_partition (N=50000 ok).

#define BN_EPS 1e-5f

typedef __attribute__((ext_vector_type(8))) short bf16x8;
typedef __attribute__((ext_vector_type(4))) float f32x4;

__device__ __forceinline__ float bf2f(unsigned short u) {
    unsigned v = ((unsigned)u) << 16;
    return __builtin_bit_cast(float, v);
}
__device__ __forceinline__ unsigned short f2bf(float f) {
    unsigned u = __builtin_bit_cast(unsigned, f);
    u += 0x7fffu + ((u >> 16) & 1u);   // round-to-nearest-even
    return (unsigned short)(u >> 16);
}

// ---------- CSR build: 2-level counting sort ----------
__global__ __launch_bounds__(256) void k_hist_coarse(const int* __restrict__ dst,
                                                     int* __restrict__ ccnt, int e) {
    __shared__ int hist[256];
    const int t = threadIdx.x;
    hist[t] = 0;
    __syncthreads();
    const int base = blockIdx.x * 4096;
    const int end = min(base + 4096, e);
    for (int idx = base + t; idx < end; idx += 256)
        atomicAdd(&hist[dst[idx] >> 8], 1);
    __syncthreads();
    if (hist[t] > 0) atomicAdd(&ccnt[t], hist[t]);
}

__global__ void k_scan_coarse(const int* __restrict__ ccnt, int* __restrict__ cbase,
                              int* __restrict__ ccur) {
    __shared__ int buf[256];
    const int t = threadIdx.x;
    const int v = ccnt[t];
    buf[t] = v;
    __syncthreads();
    for (int off = 1; off < 256; off <<= 1) {
        int add = (t >= off) ? buf[t - off] : 0;
        __syncthreads();
        buf[t] += add;
        __syncthreads();
    }
    const int ex = buf[t] - v;
    cbase[t] = ex;
    ccur[t] = ex;
    if (t == 255) cbase[256] = buf[255];
}

__global__ __launch_bounds__(256) void k_partition(const int* __restrict__ src,
                                                   const int* __restrict__ dst,
                                                   int* __restrict__ ccur,
                                                   unsigned int* __restrict__ pairs, int e) {
    __shared__ unsigned short dl[4096], sl[4096];
    __shared__ int hist[256], basel[256], rnk[256];
    const int t = threadIdx.x;
    const int base = blockIdx.x * 4096;
    hist[t] = 0; rnk[t] = 0;
    __syncthreads();
#pragma unroll
    for (int i = 0; i < 16; ++i) {
        int idx = base + t + i * 256;
        if (idx < e) {
            int d = dst[idx];
            dl[t + i * 256] = (unsigned short)d;
            sl[t + i * 256] = (unsigned short)src[idx];
            atomicAdd(&hist[d >> 8], 1);
        }
    }
    __syncthreads();
    if (hist[t] > 0) basel[t] = atomicAdd(&ccur[t], hist[t]);
    __syncthreads();
#pragma unroll
    for (int i = 0; i < 16; ++i) {
        int idx = base + t + i * 256;
        if (idx < e) {
            int d = dl[t + i * 256];
            int bb = d >> 8;
            int r = atomicAdd(&rnk[bb], 1);
            pairs[basel[bb] + r] = (unsigned)d | ((unsigned)sl[t + i * 256] << 16);
        }
    }
}

__global__ __launch_bounds__(256) void k_fine(const unsigned int* __restrict__ pairs,
                                              const int* __restrict__ cbase,
                                              int* __restrict__ rs, int* __restrict__ eb,
                                              float* __restrict__ dinv, int n, int e) {
    __shared__ int hist[256], fbase[256], cur[256], tmp[256];
    const int t = threadIdx.x;
    const int b = blockIdx.x;
    const int lo = cbase[b], hi = cbase[b + 1];
    hist[t] = 0; cur[t] = 0;
    __syncthreads();
    for (int pos = lo + t; pos < hi; pos += 256)
        atomicAdd(&hist[pairs[pos] & 255], 1);
    __syncthreads();
    const int v = hist[t];
    tmp[t] = v;
    __syncthreads();
    for (int off = 1; off < 256; off <<= 1) {
        int add = (t >= off) ? tmp[t - off] : 0;
        __syncthreads();
        tmp[t] += add;
        __syncthreads();
    }
    fbase[t] = tmp[t] - v;
    __syncthreads();
    const int node = b * 256 + t;
    if (node < n) {
        rs[node] = lo + fbase[t];
        dinv[node] = rsqrtf((float)(hist[t] + 1));  // +1 self-loop
    }
    if (b == 0 && t == 0) rs[n] = e;
    for (int pos = lo + t; pos < hi; pos += 256) {
        unsigned pr = pairs[pos];
        int local = pr & 255;
        int r = atomicAdd(&cur[local], 1);
        eb[lo + fbase[local] + r] = (int)(pr >> 16);
    }
}

// ---------- weight packing: W[k][n] fp32 -> bf16 B-fragment layout ----------
__global__ void k_packW(const float* __restrict__ W, unsigned short* __restrict__ Wp, int ncol) {
    const int nct = ncol >> 4;
    int tid = blockIdx.x * 256 + threadIdx.x;
    if (tid >= 4 * nct * 64) return;
    int lane = tid & 63;
    int f = tid >> 6;
    int ct = f % nct;
    int kc = f / nct;
    int n = ct * 16 + (lane & 15);
    int k0 = kc * 32 + (lane >> 4) * 8;
    ushort4 lo, hi;
    lo.x = f2bf(W[(size_t)(k0 + 0) * ncol + n]);
    lo.y = f2bf(W[(size_t)(k0 + 1) * ncol + n]);
    lo.z = f2bf(W[(size_t)(k0 + 2) * ncol + n]);
    lo.w = f2bf(W[(size_t)(k0 + 3) * ncol + n]);
    hi.x = f2bf(W[(size_t)(k0 + 4) * ncol + n]);
    hi.y = f2bf(W[(size_t)(k0 + 5) * ncol + n]);
    hi.z = f2bf(W[(size_t)(k0 + 6) * ncol + n]);
    hi.w = f2bf(W[(size_t)(k0 + 7) * ncol + n]);
    *(ushort4*)(Wp + (size_t)tid * 8)     = lo;
    *(ushort4*)(Wp + (size_t)tid * 8 + 4) = hi;
}

// ---------- MFMA GEMMs ----------
// Layer 1: xs[n,128](bf16) = (bf16(Af[n,128]) @ W) * dinv[row].
__global__ __launch_bounds__(256) void k_gemm_mfma128_f32(
        const float* __restrict__ Af, const unsigned short* __restrict__ Wp,
        unsigned short* __restrict__ xs, const float* __restrict__ dinv, int n) {
    __shared__ __align__(16) unsigned short Wl[16384];
    const int t = threadIdx.x;
    {
        const ushort4* s = (const ushort4*)Wp;
        ushort4* d = (ushort4*)Wl;
#pragma unroll
        for (int i = 0; i < 16; ++i) d[t + 256 * i] = s[t + 256 * i];
    }
    __syncthreads();
    const int lane = t & 63, wave = t >> 6;
    const int quad = lane >> 4, l15 = lane & 15;
    const int m0 = blockIdx.x * 64 + wave * 16;
    const int arow = min(m0 + l15, n - 1);

    f32x4 acc[8];
#pragma unroll
    for (int ct = 0; ct < 8; ++ct) acc[ct] = (f32x4){0.f, 0.f, 0.f, 0.f};

#pragma unroll
    for (int kc = 0; kc < 4; ++kc) {
        float4 alo = *(const float4*)(Af + (size_t)arow * 128 + kc * 32 + quad * 8);
        float4 ahi = *(const float4*)(Af + (size_t)arow * 128 + kc * 32 + quad * 8 + 4);
        bf16x8 a;
        a[0] = (short)f2bf(alo.x); a[1] = (short)f2bf(alo.y);
        a[2] = (short)f2bf(alo.z); a[3] = (short)f2bf(alo.w);
        a[4] = (short)f2bf(ahi.x); a[5] = (short)f2bf(ahi.y);
        a[6] = (short)f2bf(ahi.z); a[7] = (short)f2bf(ahi.w);
#pragma unroll
        for (int ct = 0; ct < 8; ++ct) {
            bf16x8 b = *(const bf16x8*)(Wl + ((kc * 8 + ct) * 64 + lane) * 8);
            acc[ct] = __builtin_amdgcn_mfma_f32_16x16x32_bf16(a, b, acc[ct], 0, 0, 0);
        }
    }

    int rowv[4]; float dvv[4];
#pragma unroll
    for (int r = 0; r < 4; ++r) {
        rowv[r] = m0 + quad * 4 + r;
        dvv[r] = dinv[min(rowv[r], n - 1)];
    }
#pragma unroll
    for (int ct = 0; ct < 8; ++ct)
#pragma unroll
        for (int r = 0; r < 4; ++r)
            if (rowv[r] < n)
                xs[(size_t)rowv[r] * 128 + ct * 16 + l15] = f2bf(acc[ct][r] * dvv[r]);
}

// Layer 2: A = relu(bn(agg))+res built on the fly; side-writes h_out (fp32 residual
// for layer 3); xs = (A@W)*dinv (bf16).
__global__ __launch_bounds__(256) void k_gemm_mfma128_bn(
        const float* __restrict__ agg, const float* __restrict__ res,
        const float* __restrict__ scale, const float* __restrict__ shift,
        float* __restrict__ h_out, const unsigned short* __restrict__ Wp,
        unsigned short* __restrict__ xs, const float* __restrict__ dinv, int n) {
    __shared__ __align__(16) unsigned short Wl[16384];
    __shared__ float s_sc[128], s_sh[128];
    const int t = threadIdx.x;
    {
        const ushort4* s = (const ushort4*)Wp;
        ushort4* d = (ushort4*)Wl;
#pragma unroll
        for (int i = 0; i < 16; ++i) d[t + 256 * i] = s[t + 256 * i];
    }
    if (t < 128) s_sc[t] = scale[t];
    else         s_sh[t - 128] = shift[t - 128];
    __syncthreads();
    const int lane = t & 63, wave = t >> 6;
    const int quad = lane >> 4, l15 = lane & 15;
    const int m0 = blockIdx.x * 64 + wave * 16;
    const int arow = min(m0 + l15, n - 1);

    f32x4 acc[8];
#pragma unroll
    for (int ct = 0; ct < 8; ++ct) acc[ct] = (f32x4){0.f, 0.f, 0.f, 0.f};

#pragma unroll
    for (int kc = 0; kc < 4; ++kc) {
        const int f = kc * 32 + quad * 8;
        float4 g0 = *(const float4*)(agg + (size_t)arow * 128 + f);
        float4 g1 = *(const float4*)(agg + (size_t)arow * 128 + f + 4);
        float4 r0 = *(const float4*)(res + (size_t)arow * 128 + f);
        float4 r1 = *(const float4*)(res + (size_t)arow * 128 + f + 4);
        float4 h0, h1;
        h0.x = fmaxf(fmaf(g0.x, s_sc[f + 0], s_sh[f + 0]), 0.f) + r0.x;
        h0.y = fmaxf(fmaf(g0.y, s_sc[f + 1], s_sh[f + 1]), 0.f) + r0.y;
        h0.z = fmaxf(fmaf(g0.z, s_sc[f + 2], s_sh[f + 2]), 0.f) + r0.z;
        h0.w = fmaxf(fmaf(g0.w, s_sc[f + 3], s_sh[f + 3]), 0.f) + r0.w;
        h1.x = fmaxf(fmaf(g1.x, s_sc[f + 4], s_sh[f + 4]), 0.f) + r1.x;
        h1.y = fmaxf(fmaf(g1.y, s_sc[f + 5], s_sh[f + 5]), 0.f) + r1.y;
        h1.z = fmaxf(fmaf(g1.z, s_sc[f + 6], s_sh[f + 6]), 0.f) + r1.z;
        h1.w = fmaxf(fmaf(g1.w, s_sc[f + 7], s_sh[f + 7]), 0.f) + r1.w;
        *(float4*)(h_out + (size_t)arow * 128 + f)     = h0;
        *(float4*)(h_out + (size_t)arow * 128 + f + 4) = h1;
        bf16x8 a;
        a[0] = (short)f2bf(h0.x); a[1] = (short)f2bf(h0.y);
        a[2] = (short)f2bf(h0.z); a[3] = (short)f2bf(h0.w);
        a[4] = (short)f2bf(h1.x); a[5] = (short)f2bf(h1.y);
        a[6] = (short)f2bf(h1.z); a[7] = (short)f2bf(h1.w);
#pragma unroll
        for (int ct = 0; ct < 8; ++ct) {
            bf16x8 b = *(const bf16x8*)(Wl + ((kc * 8 + ct) * 64 + lane) * 8);
            acc[ct] = __builtin_amdgcn_mfma_f32_16x16x32_bf16(a, b, acc[ct], 0, 0, 0);
        }
    }

    int rowv[4]; float dvv[4];
#pragma unroll
    for (int r = 0; r < 4; ++r) {
        rowv[r] = m0 + quad * 4 + r;
        dvv[r] = dinv[min(rowv[r], n - 1)];
    }
#pragma unroll
    for (int ct = 0; ct < 8; ++ct)
#pragma unroll
        for (int r = 0; r < 4; ++r)
            if (rowv[r] < n)
                xs[(size_t)rowv[r] * 128 + ct * 16 + l15] = f2bf(acc[ct][r] * dvv[r]);
}

// Layer 3: A = relu(bn(agg))+res on the fly (no side-write); xs[n,64] = (A@W64)*dinv.
__global__ __launch_bounds__(256) void k_gemm_mfma64_bn(
        const float* __restrict__ agg, const float* __restrict__ res,
        const float* __restrict__ scale, const float* __restrict__ shift,
        const unsigned short* __restrict__ Wp,
        unsigned short* __restrict__ xs, const float* __restrict__ dinv, int n) {
    __shared__ __align__(16) unsigned short Wl[8192];
    __shared__ float s_sc[128], s_sh[128];
    const int t = threadIdx.x;
    {
        const ushort4* s = (const ushort4*)Wp;
        ushort4* d = (ushort4*)Wl;
#pragma unroll
        for (int i = 0; i < 8; ++i) d[t + 256 * i] = s[t + 256 * i];
    }
    if (t < 128) s_sc[t] = scale[t];
    else         s_sh[t - 128] = shift[t - 128];
    __syncthreads();
    const int lane = t & 63, wave = t >> 6;
    const int quad = lane >> 4, l15 = lane & 15;
    const int m0 = blockIdx.x * 64 + wave * 16;
    const int arow = min(m0 + l15, n - 1);

    f32x4 acc[4];
#pragma unroll
    for (int ct = 0; ct < 4; ++ct) acc[ct] = (f32x4){0.f, 0.f, 0.f, 0.f};

#pragma unroll
    for (int kc = 0; kc < 4; ++kc) {
        const int f = kc * 32 + quad * 8;
        float4 g0 = *(const float4*)(agg + (size_t)arow * 128 + f);
        float4 g1 = *(const float4*)(agg + (size_t)arow * 128 + f + 4);
        float4 r0 = *(const float4*)(res + (size_t)arow * 128 + f);
        float4 r1 = *(const float4*)(res + (size_t)arow * 128 + f + 4);
        bf16x8 a;
        a[0] = (short)f2bf(fmaxf(fmaf(g0.x, s_sc[f + 0], s_sh[f + 0]), 0.f) + r0.x);
        a[1] = (short)f2bf(fmaxf(fmaf(g0.y, s_sc[f + 1], s_sh[f + 1]), 0.f) + r0.y);
        a[2] = (short)f2bf(fmaxf(fmaf(g0.z, s_sc[f + 2], s_sh[f + 2]), 0.f) + r0.z);
        a[3] = (short)f2bf(fmaxf(fmaf(g0.w, s_sc[f + 3], s_sh[f + 3]), 0.f) + r0.w);
        a[4] = (short)f2bf(fmaxf(fmaf(g1.x, s_sc[f + 4], s_sh[f + 4]), 0.f) + r1.x);
        a[5] = (short)f2bf(fmaxf(fmaf(g1.y, s_sc[f + 5], s_sh[f + 5]), 0.f) + r1.y);
        a[6] = (short)f2bf(fmaxf(fmaf(g1.z, s_sc[f + 6], s_sh[f + 6]), 0.f) + r1.z);
        a[7] = (short)f2bf(fmaxf(fmaf(g1.w, s_sc[f + 7], s_sh[f + 7]), 0.f) + r1.w);
#pragma unroll
        for (int ct = 0; ct < 4; ++ct) {
            bf16x8 b = *(const bf16x8*)(Wl + ((kc * 4 + ct) * 64 + lane) * 8);
            acc[ct] = __builtin_amdgcn_mfma_f32_16x16x32_bf16(a, b, acc[ct], 0, 0, 0);
        }
    }

    int rowv[4]; float dvv[4];
#pragma unroll
    for (int r = 0; r < 4; ++r) {
        rowv[r] = m0 + quad * 4 + r;
        dvv[r] = dinv[min(rowv[r], n - 1)];
    }
#pragma unroll
    for (int ct = 0; ct < 4; ++ct)
#pragma unroll
        for (int r = 0; r < 4; ++r)
            if (rowv[r] < n)
                xs[(size_t)rowv[r] * 64 + ct * 16 + l15] = f2bf(acc[ct][r] * dvv[r]);
}

// ---------- CSR gather + fused BN stats ----------
// agg[d,:] = dinv[d]*(xs[d,:]+sum xs[src,:]); also accumulates per-column
// sum/sumsq of agg into gsum/gsq (grid-stride; register accum; LDS reduce).
__global__ __launch_bounds__(256) void k_gather128_stats(
        float* __restrict__ agg, const unsigned short* __restrict__ xs,
        const int* __restrict__ rs, const int* __restrict__ eb,
        const float* __restrict__ dinv, float* __restrict__ gsum,
        float* __restrict__ gsq, int n) {
    const int t = threadIdx.x;
    const int lane = t & 31;
    const int slot = t >> 5;
    const ushort4* xv = (const ushort4*)xs;
    float sx = 0.f, sy = 0.f, sz = 0.f, sw = 0.f;
    float qx = 0.f, qy = 0.f, qz = 0.f, qw = 0.f;

    for (int node = blockIdx.x * 8 + slot; node < n; node += gridDim.x * 8) {
        ushort4 v = xv[(size_t)node * 32 + lane];
        float ax0 = bf2f(v.x), ay0 = bf2f(v.y), az0 = bf2f(v.z), aw0 = bf2f(v.w);
        float ax1 = 0.f, ay1 = 0.f, az1 = 0.f, aw1 = 0.f;
        int b = rs[node], e = rs[node + 1];
        int i = b;
        for (; i + 4 <= e; i += 4) {
            int sA = eb[i], sB = eb[i + 1], sC = eb[i + 2], sD = eb[i + 3];
            ushort4 uA = xv[(size_t)sA * 32 + lane];
            ushort4 uB = xv[(size_t)sB * 32 + lane];
            ushort4 uC = xv[(size_t)sC * 32 + lane];
            ushort4 uD = xv[(size_t)sD * 32 + lane];
            ax0 += bf2f(uA.x); ay0 += bf2f(uA.y); az0 += bf2f(uA.z); aw0 += bf2f(uA.w);
            ax1 += bf2f(uB.x); ay1 += bf2f(uB.y); az1 += bf2f(uB.z); aw1 += bf2f(uB.w);
            ax0 += bf2f(uC.x); ay0 += bf2f(uC.y); az0 += bf2f(uC.z); aw0 += bf2f(uC.w);
            ax1 += bf2f(uD.x); ay1 += bf2f(uD.y); az1 += bf2f(uD.z); aw1 += bf2f(uD.w);
        }
        for (; i < e; ++i) {
            ushort4 u = xv[(size_t)eb[i] * 32 + lane];
            ax0 += bf2f(u.x); ay0 += bf2f(u.y); az0 += bf2f(u.z); aw0 += bf2f(u.w);
        }
        float dv = dinv[node];
        float4 o;
        o.x = (ax0 + ax1) * dv; o.y = (ay0 + ay1) * dv;
        o.z = (az0 + az1) * dv; o.w = (aw0 + aw1) * dv;
        ((float4*)agg)[(size_t)node * 32 + lane] = o;
        sx += o.x; sy += o.y; sz += o.z; sw += o.w;
        qx += o.x * o.x; qy += o.y * o.y; qz += o.z * o.z; qw += o.w * o.w;
    }

    __shared__ float4 lsum[256], lsq[256];
    lsum[t] = (float4){sx, sy, sz, sw};
    lsq[t]  = (float4){qx, qy, qz, qw};
    __syncthreads();
    if (t < 32) {
        float4 a = lsum[t], b = lsq[t];
#pragma unroll
        for (int g = 1; g < 8; ++g) {
            float4 u = lsum[t + 32 * g], w = lsq[t + 32 * g];
            a.x += u.x; a.y += u.y; a.z += u.z; a.w += u.w;
            b.x += w.x; b.y += w.y; b.z += w.z; b.w += w.w;
        }
        atomicAdd(&gsum[4 * t + 0], a.x); atomicAdd(&gsum[4 * t + 1], a.y);
        atomicAdd(&gsum[4 * t + 2], a.z); atomicAdd(&gsum[4 * t + 3], a.w);
        atomicAdd(&gsq[4 * t + 0], b.x);  atomicAdd(&gsq[4 * t + 1], b.y);
        atomicAdd(&gsq[4 * t + 2], b.z);  atomicAdd(&gsq[4 * t + 3], b.w);
    }
}

__global__ void k_gather64_bias(float* __restrict__ out, const unsigned short* __restrict__ xs,
                                const int* __restrict__ rs, const int* __restrict__ eb,
                                const float* __restrict__ dinv, const float* __restrict__ bias,
                                int n) {
    int node = blockIdx.x * 16 + (threadIdx.x >> 4);
    int lane = threadIdx.x & 15;
    if (node >= n) return;
    const ushort4* xv = (const ushort4*)xs;
    ushort4 v = xv[(size_t)node * 16 + lane];
    float ax0 = bf2f(v.x), ay0 = bf2f(v.y), az0 = bf2f(v.z), aw0 = bf2f(v.w);
    float ax1 = 0.f, ay1 = 0.f, az1 = 0.f, aw1 = 0.f;
    int b = rs[node], e = rs[node + 1];
    int i = b;
    for (; i + 4 <= e; i += 4) {
        int sA = eb[i], sB = eb[i + 1], sC = eb[i + 2], sD = eb[i + 3];
        ushort4 uA = xv[(size_t)sA * 16 + lane];
        ushort4 uB = xv[(size_t)sB * 16 + lane];
        ushort4 uC = xv[(size_t)sC * 16 + lane];
        ushort4 uD = xv[(size_t)sD * 16 + lane];
        ax0 += bf2f(uA.x); ay0 += bf2f(uA.y); az0 += bf2f(uA.z); aw0 += bf2f(uA.w);
        ax1 += bf2f(uB.x); ay1 += bf2f(uB.y); az1 += bf2f(uB.z); aw1 += bf2f(uB.w);
        ax0 += bf2f(uC.x); ay0 += bf2f(uC.y); az0 += bf2f(uC.z); aw0 += bf2f(uC.w);
        ax1 += bf2f(uD.x); ay1 += bf2f(uD.y); az1 += bf2f(uD.z); aw1 += bf2f(uD.w);
    }
    for (; i < e; ++i) {
        ushort4 u = xv[(size_t)eb[i] * 16 + lane];
        ax0 += bf2f(u.x); ay0 += bf2f(u.y); az0 += bf2f(u.z); aw0 += bf2f(u.w);
    }
    float dv = dinv[node];
    const float4* bv = (const float4*)bias;
    float4 bb = bv[lane];
    float4 o;
    o.x = (ax0 + ax1) * dv + bb.x; o.y = (ay0 + ay1) * dv + bb.y;
    o.z = (az0 + az1) * dv + bb.z; o.w = (aw0 + aw1) * dv + bb.w;
    ((float4*)out)[(size_t)node * 16 + lane] = o;
}

// ---------- batch-norm finalize ----------
__global__ void k_finalize(const float* __restrict__ gsum, const float* __restrict__ gsq,
                           const float* __restrict__ gamma, const float* __restrict__ beta,
                           float* __restrict__ scale, float* __restrict__ shift, float inv_n) {
    int c = threadIdx.x;  // 128 threads
    float m = gsum[c] * inv_n;
    float v = gsq[c] * inv_n - m * m;
    float sc = gamma[c] * rsqrtf(v + BN_EPS);
    scale[c] = sc;
    shift[c] = beta[c] - m * sc;
}

extern "C" void kernel_launch(void* const* d_in, const int* in_sizes, int n_in,
                              void* d_out, int out_size, void* d_ws, size_t ws_size,
                              hipStream_t stream) {
    const float* x   = (const float*)d_in[0];
    const int*   ei  = (const int*)d_in[1];
    const float* W1  = (const float*)d_in[2];
    const float* W2  = (const float*)d_in[4];
    const float* W3  = (const float*)d_in[6];
    const float* b3  = (const float*)d_in[7];
    const float* g1  = (const float*)d_in[8];
    const float* be1 = (const float*)d_in[9];
    const float* g2  = (const float*)d_in[10];
    const float* be2 = (const float*)d_in[11];
    float* out = (float*)d_out;

    const int N = in_sizes[0] / 128;
    const int E = in_sizes[1] / 2;
    const int* src = ei;
    const int* dst = ei + E;

    char* p = (char*)d_ws;
    float* dinv  = (float*)p;               p += (size_t)N * 4;
    unsigned short* xs = (unsigned short*)p; p += (size_t)N * 128 * 2;  // GEMM output (bf16)
    float* agg   = (float*)p;               p += (size_t)N * 128 * 4;
    float* h1    = (float*)p;               p += (size_t)N * 128 * 4;
    float* gsum  = (float*)p;               p += 128 * 4;
    float* gsq   = (float*)p;               p += 128 * 4;
    float* scale = (float*)p;               p += 128 * 4;
    float* shift = (float*)p;               p += 128 * 4;
    unsigned short* Wp1 = (unsigned short*)p; p += 16384 * 2;
    unsigned short* Wp2 = (unsigned short*)p; p += 16384 * 2;
    unsigned short* Wp3 = (unsigned short*)p; p += 8192 * 2;
    int*   ccnt  = (int*)p;                 p += 256 * 4;
    int*   cbase = (int*)p;                 p += 260 * 4;   // 257 used
    int*   ccur  = (int*)p;                 p += 256 * 4;
    unsigned int* pairs = (unsigned int*)p; p += (size_t)E * 4;
    int*   rs    = (int*)p;                 p += (size_t)(N + 16) * 4;
    int*   eb    = (int*)p;                 p += (size_t)E * 4;

    const int B = 256;
    const int gT    = (N + 63) / 64;
    const int gEchk = (E + 4095) / 4096;
    const int gN256 = (N + 255) / 256;
    const int gG    = 1024;                  // gather+stats grid (grid-stride)
    const float inv_n = 1.0f / (float)N;

    // ---- CSR build (2-level counting sort) + weight packing ----
    hipMemsetAsync(ccnt, 0, 256 * 4, stream);
    k_hist_coarse<<<gEchk, B, 0, stream>>>(dst, ccnt, E);
    k_scan_coarse<<<1, B, 0, stream>>>(ccnt, cbase, ccur);
    k_partition<<<gEchk, B, 0, stream>>>(src, dst, ccur, pairs, E);
    k_fine<<<gN256, B, 0, stream>>>(pairs, cbase, rs, eb, dinv, N, E);
    k_packW<<<8, B, 0, stream>>>(W1, Wp1, 128);
    k_packW<<<8, B, 0, stream>>>(W2, Wp2, 128);
    k_packW<<<4, B, 0, stream>>>(W3, Wp3, 64);

    // ---- layer 1: xs = (bf16(x)@W1)*dinv; agg = gather (+BN1 stats) ----
    k_gemm_mfma128_f32<<<gT, B, 0, stream>>>(x, Wp1, xs, dinv, N);
    hipMemsetAsync(gsum, 0, 2 * 128 * 4, stream);
    k_gather128_stats<<<gG, B, 0, stream>>>(agg, xs, rs, eb, dinv, gsum, gsq, N);
    k_finalize<<<1, 128, 0, stream>>>(gsum, gsq, g1, be1, scale, shift, inv_n);

    // ---- layer 2: h1=relu(bn(agg))+x fused in GEMM; agg = gather (+BN2 stats) ----
    k_gemm_mfma128_bn<<<gT, B, 0, stream>>>(agg, x, scale, shift, h1, Wp2, xs, dinv, N);
    hipMemsetAsync(gsum, 0, 2 * 128 * 4, stream);
    k_gather128_stats<<<gG, B, 0, stream>>>(agg, xs, rs, eb, dinv, gsum, gsq, N);
    k_finalize<<<1, 128, 0, stream>>>(gsum, gsq, g2, be2, scale, shift, inv_n);

    // ---- layer 3: h2=relu(bn(agg))+h1 fused in GEMM; out = gather + b3 ----
    k_gemm_mfma64_bn<<<gT, B, 0, stream>>>(agg, h1, scale, shift, Wp3, xs, dinv, N);
    k_gather64_bias<<<(N + 15) / 16, B, 0, stream>>>(out, xs, rs, eb, dinv, b3, N);
}

// Round 9
// 338.373 us; speedup vs baseline: 1.4376x; 1.4376x over previous
//
#include <hip/hip_runtime.h>

// GCN encoder: 3x GCNConv (sym-norm, self-loops) + 2x BatchNorm(train)+ReLU+residual.
// N=50000, E=800000, IN=HID=128, OUT=64. fp32 in/out; edge_index int32.
//
// R2: CSR gather.  R3: reg-tiled GEMMs.  R4: hier. scan.  R5: xs bf16.
// R6: MFMA bf16 GEMMs.  R7: 2-level counting-sort CSR build.
// R8: BN+ReLU+residual fused into MFMA GEMM A-fragment build (kept).
// R9: REVERT R8's fused-stats gather (grid-stride 1024 blocks starved MLP:
//     occ 60->27%, BW 3.2->1.1 TB/s, 44->137us). Gather back to one node per
//     32-lane slot, 6250 blocks, unroll-4; separate k_stats (512 blocks).
// Gather FETCH ~113MB is near the compulsory floor (8 XCD L2s x 12.8MB xs).
// BN bias-cancel: b1/b2 vanish inside BatchNorm; only b3 applied.
// NOTE: N must be < 65536 for the u16 packing in k_partition (N=50000 ok).

#define BN_EPS 1e-5f

typedef __attribute__((ext_vector_type(8))) short bf16x8;
typedef __attribute__((ext_vector_type(4))) float f32x4;

__device__ __forceinline__ float bf2f(unsigned short u) {
    unsigned v = ((unsigned)u) << 16;
    return __builtin_bit_cast(float, v);
}
__device__ __forceinline__ unsigned short f2bf(float f) {
    unsigned u = __builtin_bit_cast(unsigned, f);
    u += 0x7fffu + ((u >> 16) & 1u);   // round-to-nearest-even
    return (unsigned short)(u >> 16);
}

// ---------- CSR build: 2-level counting sort ----------
__global__ __launch_bounds__(256) void k_hist_coarse(const int* __restrict__ dst,
                                                     int* __restrict__ ccnt, int e) {
    __shared__ int hist[256];
    const int t = threadIdx.x;
    hist[t] = 0;
    __syncthreads();
    const int base = blockIdx.x * 4096;
    const int end = min(base + 4096, e);
    for (int idx = base + t; idx < end; idx += 256)
        atomicAdd(&hist[dst[idx] >> 8], 1);
    __syncthreads();
    if (hist[t] > 0) atomicAdd(&ccnt[t], hist[t]);
}

__global__ void k_scan_coarse(const int* __restrict__ ccnt, int* __restrict__ cbase,
                              int* __restrict__ ccur) {
    __shared__ int buf[256];
    const int t = threadIdx.x;
    const int v = ccnt[t];
    buf[t] = v;
    __syncthreads();
    for (int off = 1; off < 256; off <<= 1) {
        int add = (t >= off) ? buf[t - off] : 0;
        __syncthreads();
        buf[t] += add;
        __syncthreads();
    }
    const int ex = buf[t] - v;
    cbase[t] = ex;
    ccur[t] = ex;
    if (t == 255) cbase[256] = buf[255];
}

__global__ __launch_bounds__(256) void k_partition(const int* __restrict__ src,
                                                   const int* __restrict__ dst,
                                                   int* __restrict__ ccur,
                                                   unsigned int* __restrict__ pairs, int e) {
    __shared__ unsigned short dl[4096], sl[4096];
    __shared__ int hist[256], basel[256], rnk[256];
    const int t = threadIdx.x;
    const int base = blockIdx.x * 4096;
    hist[t] = 0; rnk[t] = 0;
    __syncthreads();
#pragma unroll
    for (int i = 0; i < 16; ++i) {
        int idx = base + t + i * 256;
        if (idx < e) {
            int d = dst[idx];
            dl[t + i * 256] = (unsigned short)d;
            sl[t + i * 256] = (unsigned short)src[idx];
            atomicAdd(&hist[d >> 8], 1);
        }
    }
    __syncthreads();
    if (hist[t] > 0) basel[t] = atomicAdd(&ccur[t], hist[t]);
    __syncthreads();
#pragma unroll
    for (int i = 0; i < 16; ++i) {
        int idx = base + t + i * 256;
        if (idx < e) {
            int d = dl[t + i * 256];
            int bb = d >> 8;
            int r = atomicAdd(&rnk[bb], 1);
            pairs[basel[bb] + r] = (unsigned)d | ((unsigned)sl[t + i * 256] << 16);
        }
    }
}

__global__ __launch_bounds__(256) void k_fine(const unsigned int* __restrict__ pairs,
                                              const int* __restrict__ cbase,
                                              int* __restrict__ rs, int* __restrict__ eb,
                                              float* __restrict__ dinv, int n, int e) {
    __shared__ int hist[256], fbase[256], cur[256], tmp[256];
    const int t = threadIdx.x;
    const int b = blockIdx.x;
    const int lo = cbase[b], hi = cbase[b + 1];
    hist[t] = 0; cur[t] = 0;
    __syncthreads();
    for (int pos = lo + t; pos < hi; pos += 256)
        atomicAdd(&hist[pairs[pos] & 255], 1);
    __syncthreads();
    const int v = hist[t];
    tmp[t] = v;
    __syncthreads();
    for (int off = 1; off < 256; off <<= 1) {
        int add = (t >= off) ? tmp[t - off] : 0;
        __syncthreads();
        tmp[t] += add;
        __syncthreads();
    }
    fbase[t] = tmp[t] - v;
    __syncthreads();
    const int node = b * 256 + t;
    if (node < n) {
        rs[node] = lo + fbase[t];
        dinv[node] = rsqrtf((float)(hist[t] + 1));  // +1 self-loop
    }
    if (b == 0 && t == 0) rs[n] = e;
    for (int pos = lo + t; pos < hi; pos += 256) {
        unsigned pr = pairs[pos];
        int local = pr & 255;
        int r = atomicAdd(&cur[local], 1);
        eb[lo + fbase[local] + r] = (int)(pr >> 16);
    }
}

// ---------- weight packing: W[k][n] fp32 -> bf16 B-fragment layout ----------
__global__ void k_packW(const float* __restrict__ W, unsigned short* __restrict__ Wp, int ncol) {
    const int nct = ncol >> 4;
    int tid = blockIdx.x * 256 + threadIdx.x;
    if (tid >= 4 * nct * 64) return;
    int lane = tid & 63;
    int f = tid >> 6;
    int ct = f % nct;
    int kc = f / nct;
    int n = ct * 16 + (lane & 15);
    int k0 = kc * 32 + (lane >> 4) * 8;
    ushort4 lo, hi;
    lo.x = f2bf(W[(size_t)(k0 + 0) * ncol + n]);
    lo.y = f2bf(W[(size_t)(k0 + 1) * ncol + n]);
    lo.z = f2bf(W[(size_t)(k0 + 2) * ncol + n]);
    lo.w = f2bf(W[(size_t)(k0 + 3) * ncol + n]);
    hi.x = f2bf(W[(size_t)(k0 + 4) * ncol + n]);
    hi.y = f2bf(W[(size_t)(k0 + 5) * ncol + n]);
    hi.z = f2bf(W[(size_t)(k0 + 6) * ncol + n]);
    hi.w = f2bf(W[(size_t)(k0 + 7) * ncol + n]);
    *(ushort4*)(Wp + (size_t)tid * 8)     = lo;
    *(ushort4*)(Wp + (size_t)tid * 8 + 4) = hi;
}

// ---------- MFMA GEMMs ----------
// Layer 1: xs[n,128](bf16) = (bf16(Af[n,128]) @ W) * dinv[row].
__global__ __launch_bounds__(256) void k_gemm_mfma128_f32(
        const float* __restrict__ Af, const unsigned short* __restrict__ Wp,
        unsigned short* __restrict__ xs, const float* __restrict__ dinv, int n) {
    __shared__ __align__(16) unsigned short Wl[16384];
    const int t = threadIdx.x;
    {
        const ushort4* s = (const ushort4*)Wp;
        ushort4* d = (ushort4*)Wl;
#pragma unroll
        for (int i = 0; i < 16; ++i) d[t + 256 * i] = s[t + 256 * i];
    }
    __syncthreads();
    const int lane = t & 63, wave = t >> 6;
    const int quad = lane >> 4, l15 = lane & 15;
    const int m0 = blockIdx.x * 64 + wave * 16;
    const int arow = min(m0 + l15, n - 1);

    f32x4 acc[8];
#pragma unroll
    for (int ct = 0; ct < 8; ++ct) acc[ct] = (f32x4){0.f, 0.f, 0.f, 0.f};

#pragma unroll
    for (int kc = 0; kc < 4; ++kc) {
        float4 alo = *(const float4*)(Af + (size_t)arow * 128 + kc * 32 + quad * 8);
        float4 ahi = *(const float4*)(Af + (size_t)arow * 128 + kc * 32 + quad * 8 + 4);
        bf16x8 a;
        a[0] = (short)f2bf(alo.x); a[1] = (short)f2bf(alo.y);
        a[2] = (short)f2bf(alo.z); a[3] = (short)f2bf(alo.w);
        a[4] = (short)f2bf(ahi.x); a[5] = (short)f2bf(ahi.y);
        a[6] = (short)f2bf(ahi.z); a[7] = (short)f2bf(ahi.w);
#pragma unroll
        for (int ct = 0; ct < 8; ++ct) {
            bf16x8 b = *(const bf16x8*)(Wl + ((kc * 8 + ct) * 64 + lane) * 8);
            acc[ct] = __builtin_amdgcn_mfma_f32_16x16x32_bf16(a, b, acc[ct], 0, 0, 0);
        }
    }

    int rowv[4]; float dvv[4];
#pragma unroll
    for (int r = 0; r < 4; ++r) {
        rowv[r] = m0 + quad * 4 + r;
        dvv[r] = dinv[min(rowv[r], n - 1)];
    }
#pragma unroll
    for (int ct = 0; ct < 8; ++ct)
#pragma unroll
        for (int r = 0; r < 4; ++r)
            if (rowv[r] < n)
                xs[(size_t)rowv[r] * 128 + ct * 16 + l15] = f2bf(acc[ct][r] * dvv[r]);
}

// Layer 2: A = relu(bn(agg))+res built on the fly; side-writes h_out (fp32 residual
// for layer 3); xs = (A@W)*dinv (bf16).
__global__ __launch_bounds__(256) void k_gemm_mfma128_bn(
        const float* __restrict__ agg, const float* __restrict__ res,
        const float* __restrict__ scale, const float* __restrict__ shift,
        float* __restrict__ h_out, const unsigned short* __restrict__ Wp,
        unsigned short* __restrict__ xs, const float* __restrict__ dinv, int n) {
    __shared__ __align__(16) unsigned short Wl[16384];
    __shared__ float s_sc[128], s_sh[128];
    const int t = threadIdx.x;
    {
        const ushort4* s = (const ushort4*)Wp;
        ushort4* d = (ushort4*)Wl;
#pragma unroll
        for (int i = 0; i < 16; ++i) d[t + 256 * i] = s[t + 256 * i];
    }
    if (t < 128) s_sc[t] = scale[t];
    else         s_sh[t - 128] = shift[t - 128];
    __syncthreads();
    const int lane = t & 63, wave = t >> 6;
    const int quad = lane >> 4, l15 = lane & 15;
    const int m0 = blockIdx.x * 64 + wave * 16;
    const int arow = min(m0 + l15, n - 1);

    f32x4 acc[8];
#pragma unroll
    for (int ct = 0; ct < 8; ++ct) acc[ct] = (f32x4){0.f, 0.f, 0.f, 0.f};

#pragma unroll
    for (int kc = 0; kc < 4; ++kc) {
        const int f = kc * 32 + quad * 8;
        float4 g0 = *(const float4*)(agg + (size_t)arow * 128 + f);
        float4 g1 = *(const float4*)(agg + (size_t)arow * 128 + f + 4);
        float4 r0 = *(const float4*)(res + (size_t)arow * 128 + f);
        float4 r1 = *(const float4*)(res + (size_t)arow * 128 + f + 4);
        float4 h0, h1;
        h0.x = fmaxf(fmaf(g0.x, s_sc[f + 0], s_sh[f + 0]), 0.f) + r0.x;
        h0.y = fmaxf(fmaf(g0.y, s_sc[f + 1], s_sh[f + 1]), 0.f) + r0.y;
        h0.z = fmaxf(fmaf(g0.z, s_sc[f + 2], s_sh[f + 2]), 0.f) + r0.z;
        h0.w = fmaxf(fmaf(g0.w, s_sc[f + 3], s_sh[f + 3]), 0.f) + r0.w;
        h1.x = fmaxf(fmaf(g1.x, s_sc[f + 4], s_sh[f + 4]), 0.f) + r1.x;
        h1.y = fmaxf(fmaf(g1.y, s_sc[f + 5], s_sh[f + 5]), 0.f) + r1.y;
        h1.z = fmaxf(fmaf(g1.z, s_sc[f + 6], s_sh[f + 6]), 0.f) + r1.z;
        h1.w = fmaxf(fmaf(g1.w, s_sc[f + 7], s_sh[f + 7]), 0.f) + r1.w;
        *(float4*)(h_out + (size_t)arow * 128 + f)     = h0;
        *(float4*)(h_out + (size_t)arow * 128 + f + 4) = h1;
        bf16x8 a;
        a[0] = (short)f2bf(h0.x); a[1] = (short)f2bf(h0.y);
        a[2] = (short)f2bf(h0.z); a[3] = (short)f2bf(h0.w);
        a[4] = (short)f2bf(h1.x); a[5] = (short)f2bf(h1.y);
        a[6] = (short)f2bf(h1.z); a[7] = (short)f2bf(h1.w);
#pragma unroll
        for (int ct = 0; ct < 8; ++ct) {
            bf16x8 b = *(const bf16x8*)(Wl + ((kc * 8 + ct) * 64 + lane) * 8);
            acc[ct] = __builtin_amdgcn_mfma_f32_16x16x32_bf16(a, b, acc[ct], 0, 0, 0);
        }
    }

    int rowv[4]; float dvv[4];
#pragma unroll
    for (int r = 0; r < 4; ++r) {
        rowv[r] = m0 + quad * 4 + r;
        dvv[r] = dinv[min(rowv[r], n - 1)];
    }
#pragma unroll
    for (int ct = 0; ct < 8; ++ct)
#pragma unroll
        for (int r = 0; r < 4; ++r)
            if (rowv[r] < n)
                xs[(size_t)rowv[r] * 128 + ct * 16 + l15] = f2bf(acc[ct][r] * dvv[r]);
}

// Layer 3: A = relu(bn(agg))+res on the fly (no side-write); xs[n,64] = (A@W64)*dinv.
__global__ __launch_bounds__(256) void k_gemm_mfma64_bn(
        const float* __restrict__ agg, const float* __restrict__ res,
        const float* __restrict__ scale, const float* __restrict__ shift,
        const unsigned short* __restrict__ Wp,
        unsigned short* __restrict__ xs, const float* __restrict__ dinv, int n) {
    __shared__ __align__(16) unsigned short Wl[8192];
    __shared__ float s_sc[128], s_sh[128];
    const int t = threadIdx.x;
    {
        const ushort4* s = (const ushort4*)Wp;
        ushort4* d = (ushort4*)Wl;
#pragma unroll
        for (int i = 0; i < 8; ++i) d[t + 256 * i] = s[t + 256 * i];
    }
    if (t < 128) s_sc[t] = scale[t];
    else         s_sh[t - 128] = shift[t - 128];
    __syncthreads();
    const int lane = t & 63, wave = t >> 6;
    const int quad = lane >> 4, l15 = lane & 15;
    const int m0 = blockIdx.x * 64 + wave * 16;
    const int arow = min(m0 + l15, n - 1);

    f32x4 acc[4];
#pragma unroll
    for (int ct = 0; ct < 4; ++ct) acc[ct] = (f32x4){0.f, 0.f, 0.f, 0.f};

#pragma unroll
    for (int kc = 0; kc < 4; ++kc) {
        const int f = kc * 32 + quad * 8;
        float4 g0 = *(const float4*)(agg + (size_t)arow * 128 + f);
        float4 g1 = *(const float4*)(agg + (size_t)arow * 128 + f + 4);
        float4 r0 = *(const float4*)(res + (size_t)arow * 128 + f);
        float4 r1 = *(const float4*)(res + (size_t)arow * 128 + f + 4);
        bf16x8 a;
        a[0] = (short)f2bf(fmaxf(fmaf(g0.x, s_sc[f + 0], s_sh[f + 0]), 0.f) + r0.x);
        a[1] = (short)f2bf(fmaxf(fmaf(g0.y, s_sc[f + 1], s_sh[f + 1]), 0.f) + r0.y);
        a[2] = (short)f2bf(fmaxf(fmaf(g0.z, s_sc[f + 2], s_sh[f + 2]), 0.f) + r0.z);
        a[3] = (short)f2bf(fmaxf(fmaf(g0.w, s_sc[f + 3], s_sh[f + 3]), 0.f) + r0.w);
        a[4] = (short)f2bf(fmaxf(fmaf(g1.x, s_sc[f + 4], s_sh[f + 4]), 0.f) + r1.x);
        a[5] = (short)f2bf(fmaxf(fmaf(g1.y, s_sc[f + 5], s_sh[f + 5]), 0.f) + r1.y);
        a[6] = (short)f2bf(fmaxf(fmaf(g1.z, s_sc[f + 6], s_sh[f + 6]), 0.f) + r1.z);
        a[7] = (short)f2bf(fmaxf(fmaf(g1.w, s_sc[f + 7], s_sh[f + 7]), 0.f) + r1.w);
#pragma unroll
        for (int ct = 0; ct < 4; ++ct) {
            bf16x8 b = *(const bf16x8*)(Wl + ((kc * 4 + ct) * 64 + lane) * 8);
            acc[ct] = __builtin_amdgcn_mfma_f32_16x16x32_bf16(a, b, acc[ct], 0, 0, 0);
        }
    }

    int rowv[4]; float dvv[4];
#pragma unroll
    for (int r = 0; r < 4; ++r) {
        rowv[r] = m0 + quad * 4 + r;
        dvv[r] = dinv[min(rowv[r], n - 1)];
    }
#pragma unroll
    for (int ct = 0; ct < 4; ++ct)
#pragma unroll
        for (int r = 0; r < 4; ++r)
            if (rowv[r] < n)
                xs[(size_t)rowv[r] * 64 + ct * 16 + l15] = f2bf(acc[ct][r] * dvv[r]);
}

// ---------- CSR gather aggregation (bf16 rows, fp32 accumulate, unroll-4) ----------
__global__ void k_gather128(float* __restrict__ agg, const unsigned short* __restrict__ xs,
                            const int* __restrict__ rs, const int* __restrict__ eb,
                            const float* __restrict__ dinv, int n) {
    int node = blockIdx.x * 8 + (threadIdx.x >> 5);
    int lane = threadIdx.x & 31;
    if (node >= n) return;
    const ushort4* xv = (const ushort4*)xs;
    ushort4 v = xv[(size_t)node * 32 + lane];
    float ax0 = bf2f(v.x), ay0 = bf2f(v.y), az0 = bf2f(v.z), aw0 = bf2f(v.w);
    float ax1 = 0.f, ay1 = 0.f, az1 = 0.f, aw1 = 0.f;
    int b = rs[node], e = rs[node + 1];
    int i = b;
    for (; i + 4 <= e; i += 4) {
        int sA = eb[i], sB = eb[i + 1], sC = eb[i + 2], sD = eb[i + 3];
        ushort4 uA = xv[(size_t)sA * 32 + lane];
        ushort4 uB = xv[(size_t)sB * 32 + lane];
        ushort4 uC = xv[(size_t)sC * 32 + lane];
        ushort4 uD = xv[(size_t)sD * 32 + lane];
        ax0 += bf2f(uA.x); ay0 += bf2f(uA.y); az0 += bf2f(uA.z); aw0 += bf2f(uA.w);
        ax1 += bf2f(uB.x); ay1 += bf2f(uB.y); az1 += bf2f(uB.z); aw1 += bf2f(uB.w);
        ax0 += bf2f(uC.x); ay0 += bf2f(uC.y); az0 += bf2f(uC.z); aw0 += bf2f(uC.w);
        ax1 += bf2f(uD.x); ay1 += bf2f(uD.y); az1 += bf2f(uD.z); aw1 += bf2f(uD.w);
    }
    for (; i < e; ++i) {
        ushort4 u = xv[(size_t)eb[i] * 32 + lane];
        ax0 += bf2f(u.x); ay0 += bf2f(u.y); az0 += bf2f(u.z); aw0 += bf2f(u.w);
    }
    float dv = dinv[node];
    float4 o;
    o.x = (ax0 + ax1) * dv; o.y = (ay0 + ay1) * dv;
    o.z = (az0 + az1) * dv; o.w = (aw0 + aw1) * dv;
    ((float4*)agg)[(size_t)node * 32 + lane] = o;
}

__global__ void k_gather64_bias(float* __restrict__ out, const unsigned short* __restrict__ xs,
                                const int* __restrict__ rs, const int* __restrict__ eb,
                                const float* __restrict__ dinv, const float* __restrict__ bias,
                                int n) {
    int node = blockIdx.x * 16 + (threadIdx.x >> 4);
    int lane = threadIdx.x & 15;
    if (node >= n) return;
    const ushort4* xv = (const ushort4*)xs;
    ushort4 v = xv[(size_t)node * 16 + lane];
    float ax0 = bf2f(v.x), ay0 = bf2f(v.y), az0 = bf2f(v.z), aw0 = bf2f(v.w);
    float ax1 = 0.f, ay1 = 0.f, az1 = 0.f, aw1 = 0.f;
    int b = rs[node], e = rs[node + 1];
    int i = b;
    for (; i + 4 <= e; i += 4) {
        int sA = eb[i], sB = eb[i + 1], sC = eb[i + 2], sD = eb[i + 3];
        ushort4 uA = xv[(size_t)sA * 16 + lane];
        ushort4 uB = xv[(size_t)sB * 16 + lane];
        ushort4 uC = xv[(size_t)sC * 16 + lane];
        ushort4 uD = xv[(size_t)sD * 16 + lane];
        ax0 += bf2f(uA.x); ay0 += bf2f(uA.y); az0 += bf2f(uA.z); aw0 += bf2f(uA.w);
        ax1 += bf2f(uB.x); ay1 += bf2f(uB.y); az1 += bf2f(uB.z); aw1 += bf2f(uB.w);
        ax0 += bf2f(uC.x); ay0 += bf2f(uC.y); az0 += bf2f(uC.z); aw0 += bf2f(uC.w);
        ax1 += bf2f(uD.x); ay1 += bf2f(uD.y); az1 += bf2f(uD.z); aw1 += bf2f(uD.w);
    }
    for (; i < e; ++i) {
        ushort4 u = xv[(size_t)eb[i] * 16 + lane];
        ax0 += bf2f(u.x); ay0 += bf2f(u.y); az0 += bf2f(u.z); aw0 += bf2f(u.w);
    }
    float dv = dinv[node];
    const float4* bv = (const float4*)bias;
    float4 bb = bv[lane];
    float4 o;
    o.x = (ax0 + ax1) * dv + bb.x; o.y = (ay0 + ay1) * dv + bb.y;
    o.z = (az0 + az1) * dv + bb.z; o.w = (aw0 + aw1) * dv + bb.w;
    ((float4*)out)[(size_t)node * 16 + lane] = o;
}

// ---------- batch-norm ----------
__global__ void k_stats(const float* __restrict__ h, float* __restrict__ gsum,
                        float* __restrict__ gsq, int n) {
    int c = threadIdx.x & 127;
    int half = threadIdx.x >> 7;
    float s = 0.f, s2 = 0.f;
    for (int r = blockIdx.x * 2 + half; r < n; r += gridDim.x * 2) {
        float v = h[(size_t)r * 128 + c];
        s += v; s2 += v * v;
    }
    __shared__ float ls[256], ls2[256];
    ls[threadIdx.x] = s; ls2[threadIdx.x] = s2;
    __syncthreads();
    if (threadIdx.x < 128) {
        atomicAdd(&gsum[c], ls[threadIdx.x] + ls[threadIdx.x + 128]);
        atomicAdd(&gsq[c],  ls2[threadIdx.x] + ls2[threadIdx.x + 128]);
    }
}

__global__ void k_finalize(const float* __restrict__ gsum, const float* __restrict__ gsq,
                           const float* __restrict__ gamma, const float* __restrict__ beta,
                           float* __restrict__ scale, float* __restrict__ shift, float inv_n) {
    int c = threadIdx.x;  // 128 threads
    float m = gsum[c] * inv_n;
    float v = gsq[c] * inv_n - m * m;
    float sc = gamma[c] * rsqrtf(v + BN_EPS);
    scale[c] = sc;
    shift[c] = beta[c] - m * sc;
}

extern "C" void kernel_launch(void* const* d_in, const int* in_sizes, int n_in,
                              void* d_out, int out_size, void* d_ws, size_t ws_size,
                              hipStream_t stream) {
    const float* x   = (const float*)d_in[0];
    const int*   ei  = (const int*)d_in[1];
    const float* W1  = (const float*)d_in[2];
    const float* W2  = (const float*)d_in[4];
    const float* W3  = (const float*)d_in[6];
    const float* b3  = (const float*)d_in[7];
    const float* g1  = (const float*)d_in[8];
    const float* be1 = (const float*)d_in[9];
    const float* g2  = (const float*)d_in[10];
    const float* be2 = (const float*)d_in[11];
    float* out = (float*)d_out;

    const int N = in_sizes[0] / 128;
    const int E = in_sizes[1] / 2;
    const int* src = ei;
    const int* dst = ei + E;

    char* p = (char*)d_ws;
    float* dinv  = (float*)p;               p += (size_t)N * 4;
    unsigned short* xs = (unsigned short*)p; p += (size_t)N * 128 * 2;  // GEMM output (bf16)
    float* agg   = (float*)p;               p += (size_t)N * 128 * 4;
    float* h1    = (float*)p;               p += (size_t)N * 128 * 4;
    float* gsum  = (float*)p;               p += 128 * 4;
    float* gsq   = (float*)p;               p += 128 * 4;
    float* scale = (float*)p;               p += 128 * 4;
    float* shift = (float*)p;               p += 128 * 4;
    unsigned short* Wp1 = (unsigned short*)p; p += 16384 * 2;
    unsigned short* Wp2 = (unsigned short*)p; p += 16384 * 2;
    unsigned short* Wp3 = (unsigned short*)p; p += 8192 * 2;
    int*   ccnt  = (int*)p;                 p += 256 * 4;
    int*   cbase = (int*)p;                 p += 260 * 4;   // 257 used
    int*   ccur  = (int*)p;                 p += 256 * 4;
    unsigned int* pairs = (unsigned int*)p; p += (size_t)E * 4;
    int*   rs    = (int*)p;                 p += (size_t)(N + 16) * 4;
    int*   eb    = (int*)p;                 p += (size_t)E * 4;

    const int B = 256;
    const int gT    = (N + 63) / 64;
    const int gEchk = (E + 4095) / 4096;
    const int gN256 = (N + 255) / 256;
    const float inv_n = 1.0f / (float)N;

    // ---- CSR build (2-level counting sort) + weight packing ----
    hipMemsetAsync(ccnt, 0, 256 * 4, stream);
    k_hist_coarse<<<gEchk, B, 0, stream>>>(dst, ccnt, E);
    k_scan_coarse<<<1, B, 0, stream>>>(ccnt, cbase, ccur);
    k_partition<<<gEchk, B, 0, stream>>>(src, dst, ccur, pairs, E);
    k_fine<<<gN256, B, 0, stream>>>(pairs, cbase, rs, eb, dinv, N, E);
    k_packW<<<8, B, 0, stream>>>(W1, Wp1, 128);
    k_packW<<<8, B, 0, stream>>>(W2, Wp2, 128);
    k_packW<<<4, B, 0, stream>>>(W3, Wp3, 64);

    // ---- layer 1: xs = (bf16(x)@W1)*dinv; agg = gather; BN1 stats ----
    k_gemm_mfma128_f32<<<gT, B, 0, stream>>>(x, Wp1, xs, dinv, N);
    k_gather128<<<(N + 7) / 8, B, 0, stream>>>(agg, xs, rs, eb, dinv, N);
    hipMemsetAsync(gsum, 0, 2 * 128 * 4, stream);
    k_stats<<<512, B, 0, stream>>>(agg, gsum, gsq, N);
    k_finalize<<<1, 128, 0, stream>>>(gsum, gsq, g1, be1, scale, shift, inv_n);

    // ---- layer 2: h1=relu(bn(agg))+x fused in GEMM; agg = gather; BN2 stats ----
    k_gemm_mfma128_bn<<<gT, B, 0, stream>>>(agg, x, scale, shift, h1, Wp2, xs, dinv, N);
    k_gather128<<<(N + 7) / 8, B, 0, stream>>>(agg, xs, rs, eb, dinv, N);
    hipMemsetAsync(gsum, 0, 2 * 128 * 4, stream);
    k_stats<<<512, B, 0, stream>>>(agg, gsum, gsq, N);
    k_finalize<<<1, 128, 0, stream>>>(gsum, gsq, g2, be2, scale, shift, inv_n);

    // ---- layer 3: h2=relu(bn(agg))+h1 fused in GEMM; out = gather + b3 ----
    k_gemm_mfma64_bn<<<gT, B, 0, stream>>>(agg, h1, scale, shift, Wp3, xs, dinv, N);
    k_gather64_bias<<<(N + 15) / 16, B, 0, stream>>>(out, xs, rs, eb, dinv, b3, N);
}

// Round 10
// 316.464 us; speedup vs baseline: 1.5371x; 1.0692x over previous
//
#include <hip/hip_runtime.h>

// GCN encoder: 3x GCNConv (sym-norm, self-loops) + 2x BatchNorm(train)+ReLU+residual.
// N=50000, E=800000, IN=HID=128, OUT=64. fp32 in/out; edge_index int32.
//
// R2: CSR gather.  R3: reg-tiled GEMMs.  R4: hier. scan.  R5: xs bf16.
// R6: MFMA bf16 GEMMs.  R7: 2-level counting-sort CSR build.
// R8: BN+ReLU+residual fused into MFMA GEMM A-fragment build.
// R9: gather back to 6250 independent blocks (grid-stride starved MLP).
// R10: BN stats fused into gather WITHOUT grid shrink (register partials +
//      LDS reduce -> per-block scratch; 128-block colreduce). finalize folded
//      into GEMM staging (scale/shift from gsum/gsq/gamma/beta in LDS step).
//      h1 residual stored bf16 (= the GEMM A fragment bits). packW merged.
//      Dispatches 22 -> 14.
// Gather FETCH ~113MB is near the compulsory floor (8 XCD L2s x 12.8MB xs).
// BN bias-cancel: b1/b2 vanish inside BatchNorm; only b3 applied.
// NOTE: N must be < 65536 for the u16 packing in k_partition (N=50000 ok).

#define BN_EPS 1e-5f

typedef __attribute__((ext_vector_type(8))) short bf16x8;
typedef __attribute__((ext_vector_type(4))) float f32x4;

__device__ __forceinline__ float bf2f(unsigned short u) {
    unsigned v = ((unsigned)u) << 16;
    return __builtin_bit_cast(float, v);
}
__device__ __forceinline__ unsigned short f2bf(float f) {
    unsigned u = __builtin_bit_cast(unsigned, f);
    u += 0x7fffu + ((u >> 16) & 1u);   // round-to-nearest-even
    return (unsigned short)(u >> 16);
}

// ---------- CSR build: 2-level counting sort ----------
__global__ __launch_bounds__(256) void k_hist_coarse(const int* __restrict__ dst,
                                                     int* __restrict__ ccnt, int e) {
    __shared__ int hist[256];
    const int t = threadIdx.x;
    hist[t] = 0;
    __syncthreads();
    const int base = blockIdx.x * 4096;
    const int end = min(base + 4096, e);
    for (int idx = base + t; idx < end; idx += 256)
        atomicAdd(&hist[dst[idx] >> 8], 1);
    __syncthreads();
    if (hist[t] > 0) atomicAdd(&ccnt[t], hist[t]);
}

__global__ void k_scan_coarse(const int* __restrict__ ccnt, int* __restrict__ cbase,
                              int* __restrict__ ccur) {
    __shared__ int buf[256];
    const int t = threadIdx.x;
    const int v = ccnt[t];
    buf[t] = v;
    __syncthreads();
    for (int off = 1; off < 256; off <<= 1) {
        int add = (t >= off) ? buf[t - off] : 0;
        __syncthreads();
        buf[t] += add;
        __syncthreads();
    }
    const int ex = buf[t] - v;
    cbase[t] = ex;
    ccur[t] = ex;
    if (t == 255) cbase[256] = buf[255];
}

__global__ __launch_bounds__(256) void k_partition(const int* __restrict__ src,
                                                   const int* __restrict__ dst,
                                                   int* __restrict__ ccur,
                                                   unsigned int* __restrict__ pairs, int e) {
    __shared__ unsigned short dl[4096], sl[4096];
    __shared__ int hist[256], basel[256], rnk[256];
    const int t = threadIdx.x;
    const int base = blockIdx.x * 4096;
    hist[t] = 0; rnk[t] = 0;
    __syncthreads();
#pragma unroll
    for (int i = 0; i < 16; ++i) {
        int idx = base + t + i * 256;
        if (idx < e) {
            int d = dst[idx];
            dl[t + i * 256] = (unsigned short)d;
            sl[t + i * 256] = (unsigned short)src[idx];
            atomicAdd(&hist[d >> 8], 1);
        }
    }
    __syncthreads();
    if (hist[t] > 0) basel[t] = atomicAdd(&ccur[t], hist[t]);
    __syncthreads();
#pragma unroll
    for (int i = 0; i < 16; ++i) {
        int idx = base + t + i * 256;
        if (idx < e) {
            int d = dl[t + i * 256];
            int bb = d >> 8;
            int r = atomicAdd(&rnk[bb], 1);
            pairs[basel[bb] + r] = (unsigned)d | ((unsigned)sl[t + i * 256] << 16);
        }
    }
}

__global__ __launch_bounds__(256) void k_fine(const unsigned int* __restrict__ pairs,
                                              const int* __restrict__ cbase,
                                              int* __restrict__ rs, int* __restrict__ eb,
                                              float* __restrict__ dinv, int n, int e) {
    __shared__ int hist[256], fbase[256], cur[256], tmp[256];
    const int t = threadIdx.x;
    const int b = blockIdx.x;
    const int lo = cbase[b], hi = cbase[b + 1];
    hist[t] = 0; cur[t] = 0;
    __syncthreads();
    for (int pos = lo + t; pos < hi; pos += 256)
        atomicAdd(&hist[pairs[pos] & 255], 1);
    __syncthreads();
    const int v = hist[t];
    tmp[t] = v;
    __syncthreads();
    for (int off = 1; off < 256; off <<= 1) {
        int add = (t >= off) ? tmp[t - off] : 0;
        __syncthreads();
        tmp[t] += add;
        __syncthreads();
    }
    fbase[t] = tmp[t] - v;
    __syncthreads();
    const int node = b * 256 + t;
    if (node < n) {
        rs[node] = lo + fbase[t];
        dinv[node] = rsqrtf((float)(hist[t] + 1));  // +1 self-loop
    }
    if (b == 0 && t == 0) rs[n] = e;
    for (int pos = lo + t; pos < hi; pos += 256) {
        unsigned pr = pairs[pos];
        int local = pr & 255;
        int r = atomicAdd(&cur[local], 1);
        eb[lo + fbase[local] + r] = (int)(pr >> 16);
    }
}

// ---------- weight packing (all 3 weights in one dispatch) ----------
__device__ __forceinline__ void packW_one(const float* __restrict__ W,
                                          unsigned short* __restrict__ Wp,
                                          int ncol, int tid) {
    const int nct = ncol >> 4;
    int lane = tid & 63;
    int f = tid >> 6;
    int ct = f % nct;
    int kc = f / nct;
    int n = ct * 16 + (lane & 15);
    int k0 = kc * 32 + (lane >> 4) * 8;
    ushort4 lo, hi;
    lo.x = f2bf(W[(size_t)(k0 + 0) * ncol + n]);
    lo.y = f2bf(W[(size_t)(k0 + 1) * ncol + n]);
    lo.z = f2bf(W[(size_t)(k0 + 2) * ncol + n]);
    lo.w = f2bf(W[(size_t)(k0 + 3) * ncol + n]);
    hi.x = f2bf(W[(size_t)(k0 + 4) * ncol + n]);
    hi.y = f2bf(W[(size_t)(k0 + 5) * ncol + n]);
    hi.z = f2bf(W[(size_t)(k0 + 6) * ncol + n]);
    hi.w = f2bf(W[(size_t)(k0 + 7) * ncol + n]);
    *(ushort4*)(Wp + (size_t)tid * 8)     = lo;
    *(ushort4*)(Wp + (size_t)tid * 8 + 4) = hi;
}

__global__ void k_packW_all(const float* __restrict__ W1, const float* __restrict__ W2,
                            const float* __restrict__ W3,
                            unsigned short* __restrict__ Wp1, unsigned short* __restrict__ Wp2,
                            unsigned short* __restrict__ Wp3) {
    int tid = blockIdx.x * 256 + threadIdx.x;
    if (tid < 2048)      packW_one(W1, Wp1, 128, tid);
    else if (tid < 4096) packW_one(W2, Wp2, 128, tid - 2048);
    else if (tid < 5120) packW_one(W3, Wp3, 64, tid - 4096);
}

// ---------- MFMA GEMMs ----------
// Layer 1: xs[n,128](bf16) = (bf16(Af[n,128]) @ W) * dinv[row].
__global__ __launch_bounds__(256) void k_gemm_mfma128_f32(
        const float* __restrict__ Af, const unsigned short* __restrict__ Wp,
        unsigned short* __restrict__ xs, const float* __restrict__ dinv, int n) {
    __shared__ __align__(16) unsigned short Wl[16384];
    const int t = threadIdx.x;
    {
        const ushort4* s = (const ushort4*)Wp;
        ushort4* d = (ushort4*)Wl;
#pragma unroll
        for (int i = 0; i < 16; ++i) d[t + 256 * i] = s[t + 256 * i];
    }
    __syncthreads();
    const int lane = t & 63, wave = t >> 6;
    const int quad = lane >> 4, l15 = lane & 15;
    const int m0 = blockIdx.x * 64 + wave * 16;
    const int arow = min(m0 + l15, n - 1);

    f32x4 acc[8];
#pragma unroll
    for (int ct = 0; ct < 8; ++ct) acc[ct] = (f32x4){0.f, 0.f, 0.f, 0.f};

#pragma unroll
    for (int kc = 0; kc < 4; ++kc) {
        float4 alo = *(const float4*)(Af + (size_t)arow * 128 + kc * 32 + quad * 8);
        float4 ahi = *(const float4*)(Af + (size_t)arow * 128 + kc * 32 + quad * 8 + 4);
        bf16x8 a;
        a[0] = (short)f2bf(alo.x); a[1] = (short)f2bf(alo.y);
        a[2] = (short)f2bf(alo.z); a[3] = (short)f2bf(alo.w);
        a[4] = (short)f2bf(ahi.x); a[5] = (short)f2bf(ahi.y);
        a[6] = (short)f2bf(ahi.z); a[7] = (short)f2bf(ahi.w);
#pragma unroll
        for (int ct = 0; ct < 8; ++ct) {
            bf16x8 b = *(const bf16x8*)(Wl + ((kc * 8 + ct) * 64 + lane) * 8);
            acc[ct] = __builtin_amdgcn_mfma_f32_16x16x32_bf16(a, b, acc[ct], 0, 0, 0);
        }
    }

    int rowv[4]; float dvv[4];
#pragma unroll
    for (int r = 0; r < 4; ++r) {
        rowv[r] = m0 + quad * 4 + r;
        dvv[r] = dinv[min(rowv[r], n - 1)];
    }
#pragma unroll
    for (int ct = 0; ct < 8; ++ct)
#pragma unroll
        for (int r = 0; r < 4; ++r)
            if (rowv[r] < n)
                xs[(size_t)rowv[r] * 128 + ct * 16 + l15] = f2bf(acc[ct][r] * dvv[r]);
}

// Layer 2: BN params computed in-block from gsum/gsq/gamma/beta (finalize folded);
// A = relu(bn(agg))+res(fp32 x); side-writes bf16 residual h_out (= A fragment bits);
// xs = (A@W)*dinv.
__global__ __launch_bounds__(256) void k_gemm_mfma128_bn(
        const float* __restrict__ agg, const float* __restrict__ res,
        const float* __restrict__ gsum, const float* __restrict__ gsq,
        const float* __restrict__ gamma, const float* __restrict__ beta, float inv_n,
        unsigned short* __restrict__ h_out, const unsigned short* __restrict__ Wp,
        unsigned short* __restrict__ xs, const float* __restrict__ dinv, int n) {
    __shared__ __align__(16) unsigned short Wl[16384];
    __shared__ float s_sc[128], s_sh[128];
    const int t = threadIdx.x;
    {
        const ushort4* s = (const ushort4*)Wp;
        ushort4* d = (ushort4*)Wl;
#pragma unroll
        for (int i = 0; i < 16; ++i) d[t + 256 * i] = s[t + 256 * i];
    }
    if (t < 128) {
        float m = gsum[t] * inv_n;
        float v = gsq[t] * inv_n - m * m;
        float sc = gamma[t] * rsqrtf(v + BN_EPS);
        s_sc[t] = sc;
        s_sh[t] = beta[t] - m * sc;
    }
    __syncthreads();
    const int lane = t & 63, wave = t >> 6;
    const int quad = lane >> 4, l15 = lane & 15;
    const int m0 = blockIdx.x * 64 + wave * 16;
    const int arow = min(m0 + l15, n - 1);

    f32x4 acc[8];
#pragma unroll
    for (int ct = 0; ct < 8; ++ct) acc[ct] = (f32x4){0.f, 0.f, 0.f, 0.f};

#pragma unroll
    for (int kc = 0; kc < 4; ++kc) {
        const int f = kc * 32 + quad * 8;
        float4 g0 = *(const float4*)(agg + (size_t)arow * 128 + f);
        float4 g1 = *(const float4*)(agg + (size_t)arow * 128 + f + 4);
        float4 r0 = *(const float4*)(res + (size_t)arow * 128 + f);
        float4 r1 = *(const float4*)(res + (size_t)arow * 128 + f + 4);
        bf16x8 a;
        a[0] = (short)f2bf(fmaxf(fmaf(g0.x, s_sc[f + 0], s_sh[f + 0]), 0.f) + r0.x);
        a[1] = (short)f2bf(fmaxf(fmaf(g0.y, s_sc[f + 1], s_sh[f + 1]), 0.f) + r0.y);
        a[2] = (short)f2bf(fmaxf(fmaf(g0.z, s_sc[f + 2], s_sh[f + 2]), 0.f) + r0.z);
        a[3] = (short)f2bf(fmaxf(fmaf(g0.w, s_sc[f + 3], s_sh[f + 3]), 0.f) + r0.w);
        a[4] = (short)f2bf(fmaxf(fmaf(g1.x, s_sc[f + 4], s_sh[f + 4]), 0.f) + r1.x);
        a[5] = (short)f2bf(fmaxf(fmaf(g1.y, s_sc[f + 5], s_sh[f + 5]), 0.f) + r1.y);
        a[6] = (short)f2bf(fmaxf(fmaf(g1.z, s_sc[f + 6], s_sh[f + 6]), 0.f) + r1.z);
        a[7] = (short)f2bf(fmaxf(fmaf(g1.w, s_sc[f + 7], s_sh[f + 7]), 0.f) + r1.w);
        *(bf16x8*)(h_out + (size_t)arow * 128 + f) = a;   // bf16 residual for layer 3
#pragma unroll
        for (int ct = 0; ct < 8; ++ct) {
            bf16x8 b = *(const bf16x8*)(Wl + ((kc * 8 + ct) * 64 + lane) * 8);
            acc[ct] = __builtin_amdgcn_mfma_f32_16x16x32_bf16(a, b, acc[ct], 0, 0, 0);
        }
    }

    int rowv[4]; float dvv[4];
#pragma unroll
    for (int r = 0; r < 4; ++r) {
        rowv[r] = m0 + quad * 4 + r;
        dvv[r] = dinv[min(rowv[r], n - 1)];
    }
#pragma unroll
    for (int ct = 0; ct < 8; ++ct)
#pragma unroll
        for (int r = 0; r < 4; ++r)
            if (rowv[r] < n)
                xs[(size_t)rowv[r] * 128 + ct * 16 + l15] = f2bf(acc[ct][r] * dvv[r]);
}

// Layer 3: BN params in-block; res is bf16; xs[n,64] = (A@W64)*dinv.
__global__ __launch_bounds__(256) void k_gemm_mfma64_bn(
        const float* __restrict__ agg, const unsigned short* __restrict__ res,
        const float* __restrict__ gsum, const float* __restrict__ gsq,
        const float* __restrict__ gamma, const float* __restrict__ beta, float inv_n,
        const unsigned short* __restrict__ Wp,
        unsigned short* __restrict__ xs, const float* __restrict__ dinv, int n) {
    __shared__ __align__(16) unsigned short Wl[8192];
    __shared__ float s_sc[128], s_sh[128];
    const int t = threadIdx.x;
    {
        const ushort4* s = (const ushort4*)Wp;
        ushort4* d = (ushort4*)Wl;
#pragma unroll
        for (int i = 0; i < 8; ++i) d[t + 256 * i] = s[t + 256 * i];
    }
    if (t < 128) {
        float m = gsum[t] * inv_n;
        float v = gsq[t] * inv_n - m * m;
        float sc = gamma[t] * rsqrtf(v + BN_EPS);
        s_sc[t] = sc;
        s_sh[t] = beta[t] - m * sc;
    }
    __syncthreads();
    const int lane = t & 63, wave = t >> 6;
    const int quad = lane >> 4, l15 = lane & 15;
    const int m0 = blockIdx.x * 64 + wave * 16;
    const int arow = min(m0 + l15, n - 1);

    f32x4 acc[4];
#pragma unroll
    for (int ct = 0; ct < 4; ++ct) acc[ct] = (f32x4){0.f, 0.f, 0.f, 0.f};

#pragma unroll
    for (int kc = 0; kc < 4; ++kc) {
        const int f = kc * 32 + quad * 8;
        float4 g0 = *(const float4*)(agg + (size_t)arow * 128 + f);
        float4 g1 = *(const float4*)(agg + (size_t)arow * 128 + f + 4);
        bf16x8 rv = *(const bf16x8*)(res + (size_t)arow * 128 + f);
        bf16x8 a;
        a[0] = (short)f2bf(fmaxf(fmaf(g0.x, s_sc[f + 0], s_sh[f + 0]), 0.f) + bf2f((unsigned short)rv[0]));
        a[1] = (short)f2bf(fmaxf(fmaf(g0.y, s_sc[f + 1], s_sh[f + 1]), 0.f) + bf2f((unsigned short)rv[1]));
        a[2] = (short)f2bf(fmaxf(fmaf(g0.z, s_sc[f + 2], s_sh[f + 2]), 0.f) + bf2f((unsigned short)rv[2]));
        a[3] = (short)f2bf(fmaxf(fmaf(g0.w, s_sc[f + 3], s_sh[f + 3]), 0.f) + bf2f((unsigned short)rv[3]));
        a[4] = (short)f2bf(fmaxf(fmaf(g1.x, s_sc[f + 4], s_sh[f + 4]), 0.f) + bf2f((unsigned short)rv[4]));
        a[5] = (short)f2bf(fmaxf(fmaf(g1.y, s_sc[f + 5], s_sh[f + 5]), 0.f) + bf2f((unsigned short)rv[5]));
        a[6] = (short)f2bf(fmaxf(fmaf(g1.z, s_sc[f + 6], s_sh[f + 6]), 0.f) + bf2f((unsigned short)rv[6]));
        a[7] = (short)f2bf(fmaxf(fmaf(g1.w, s_sc[f + 7], s_sh[f + 7]), 0.f) + bf2f((unsigned short)rv[7]));
#pragma unroll
        for (int ct = 0; ct < 4; ++ct) {
            bf16x8 b = *(const bf16x8*)(Wl + ((kc * 4 + ct) * 64 + lane) * 8);
            acc[ct] = __builtin_amdgcn_mfma_f32_16x16x32_bf16(a, b, acc[ct], 0, 0, 0);
        }
    }

    int rowv[4]; float dvv[4];
#pragma unroll
    for (int r = 0; r < 4; ++r) {
        rowv[r] = m0 + quad * 4 + r;
        dvv[r] = dinv[min(rowv[r], n - 1)];
    }
#pragma unroll
    for (int ct = 0; ct < 4; ++ct)
#pragma unroll
        for (int r = 0; r < 4; ++r)
            if (rowv[r] < n)
                xs[(size_t)rowv[r] * 64 + ct * 16 + l15] = f2bf(acc[ct][r] * dvv[r]);
}

// ---------- CSR gather + per-block BN stat partials (keeps 6250-block shape) ----------
// agg[d,:] = dinv[d]*(xs[d,:]+sum xs[src,:]); per-block column sum/sumsq partials
// written to scratch[block*256 + {0..127 sums, 128..255 sqs}].
__global__ __launch_bounds__(256) void k_gather128(
        float* __restrict__ agg, const unsigned short* __restrict__ xs,
        const int* __restrict__ rs, const int* __restrict__ eb,
        const float* __restrict__ dinv, float* __restrict__ scratch, int n) {
    const int t = threadIdx.x;
    const int lane = t & 31;
    const int node = blockIdx.x * 8 + (t >> 5);
    const ushort4* xv = (const ushort4*)xs;
    float4 o = {0.f, 0.f, 0.f, 0.f};
    if (node < n) {
        ushort4 v = xv[(size_t)node * 32 + lane];
        float ax0 = bf2f(v.x), ay0 = bf2f(v.y), az0 = bf2f(v.z), aw0 = bf2f(v.w);
        float ax1 = 0.f, ay1 = 0.f, az1 = 0.f, aw1 = 0.f;
        int b = rs[node], e = rs[node + 1];
        int i = b;
        for (; i + 4 <= e; i += 4) {
            int sA = eb[i], sB = eb[i + 1], sC = eb[i + 2], sD = eb[i + 3];
            ushort4 uA = xv[(size_t)sA * 32 + lane];
            ushort4 uB = xv[(size_t)sB * 32 + lane];
            ushort4 uC = xv[(size_t)sC * 32 + lane];
            ushort4 uD = xv[(size_t)sD * 32 + lane];
            ax0 += bf2f(uA.x); ay0 += bf2f(uA.y); az0 += bf2f(uA.z); aw0 += bf2f(uA.w);
            ax1 += bf2f(uB.x); ay1 += bf2f(uB.y); az1 += bf2f(uB.z); aw1 += bf2f(uB.w);
            ax0 += bf2f(uC.x); ay0 += bf2f(uC.y); az0 += bf2f(uC.z); aw0 += bf2f(uC.w);
            ax1 += bf2f(uD.x); ay1 += bf2f(uD.y); az1 += bf2f(uD.z); aw1 += bf2f(uD.w);
        }
        for (; i < e; ++i) {
            ushort4 u = xv[(size_t)eb[i] * 32 + lane];
            ax0 += bf2f(u.x); ay0 += bf2f(u.y); az0 += bf2f(u.z); aw0 += bf2f(u.w);
        }
        float dv = dinv[node];
        o.x = (ax0 + ax1) * dv; o.y = (ay0 + ay1) * dv;
        o.z = (az0 + az1) * dv; o.w = (aw0 + aw1) * dv;
        ((float4*)agg)[(size_t)node * 32 + lane] = o;
    }
    // stats partials: columns lane*4..lane*4+3; reduce across the 8 slots.
    __shared__ float4 lsum[256], lsq[256];
    lsum[t] = o;
    lsq[t]  = (float4){o.x * o.x, o.y * o.y, o.z * o.z, o.w * o.w};
    __syncthreads();
    if (t < 32) {
        float4 a = lsum[t], b = lsq[t];
#pragma unroll
        for (int g = 1; g < 8; ++g) {
            float4 u = lsum[t + 32 * g], w = lsq[t + 32 * g];
            a.x += u.x; a.y += u.y; a.z += u.z; a.w += u.w;
            b.x += w.x; b.y += w.y; b.z += w.z; b.w += w.w;
        }
        ((float4*)scratch)[(size_t)blockIdx.x * 64 + t]      = a;  // cols 4t..4t+3 sums
        ((float4*)scratch)[(size_t)blockIdx.x * 64 + 32 + t] = b;  // sqs
    }
}

// Reduce per-block partials -> gsum/gsq (one block per column).
__global__ __launch_bounds__(256) void k_colreduce(const float* __restrict__ scratch,
                                                   float* __restrict__ gsum,
                                                   float* __restrict__ gsq, int nblk) {
    const int c = blockIdx.x;   // 0..127
    const int t = threadIdx.x;
    float s = 0.f, q = 0.f;
    for (int b = t; b < nblk; b += 256) {
        s += scratch[(size_t)b * 256 + c];
        q += scratch[(size_t)b * 256 + 128 + c];
    }
    __shared__ float ls[256], lq[256];
    ls[t] = s; lq[t] = q;
    __syncthreads();
    for (int off = 128; off; off >>= 1) {
        if (t < off) { ls[t] += ls[t + off]; lq[t] += lq[t + off]; }
        __syncthreads();
    }
    if (t == 0) { gsum[c] = ls[0]; gsq[c] = lq[0]; }
}

__global__ void k_gather64_bias(float* __restrict__ out, const unsigned short* __restrict__ xs,
                                const int* __restrict__ rs, const int* __restrict__ eb,
                                const float* __restrict__ dinv, const float* __restrict__ bias,
                                int n) {
    int node = blockIdx.x * 16 + (threadIdx.x >> 4);
    int lane = threadIdx.x & 15;
    if (node >= n) return;
    const ushort4* xv = (const ushort4*)xs;
    ushort4 v = xv[(size_t)node * 16 + lane];
    float ax0 = bf2f(v.x), ay0 = bf2f(v.y), az0 = bf2f(v.z), aw0 = bf2f(v.w);
    float ax1 = 0.f, ay1 = 0.f, az1 = 0.f, aw1 = 0.f;
    int b = rs[node], e = rs[node + 1];
    int i = b;
    for (; i + 4 <= e; i += 4) {
        int sA = eb[i], sB = eb[i + 1], sC = eb[i + 2], sD = eb[i + 3];
        ushort4 uA = xv[(size_t)sA * 16 + lane];
        ushort4 uB = xv[(size_t)sB * 16 + lane];
        ushort4 uC = xv[(size_t)sC * 16 + lane];
        ushort4 uD = xv[(size_t)sD * 16 + lane];
        ax0 += bf2f(uA.x); ay0 += bf2f(uA.y); az0 += bf2f(uA.z); aw0 += bf2f(uA.w);
        ax1 += bf2f(uB.x); ay1 += bf2f(uB.y); az1 += bf2f(uB.z); aw1 += bf2f(uB.w);
        ax0 += bf2f(uC.x); ay0 += bf2f(uC.y); az0 += bf2f(uC.z); aw0 += bf2f(uC.w);
        ax1 += bf2f(uD.x); ay1 += bf2f(uD.y); az1 += bf2f(uD.z); aw1 += bf2f(uD.w);
    }
    for (; i < e; ++i) {
        ushort4 u = xv[(size_t)eb[i] * 16 + lane];
        ax0 += bf2f(u.x); ay0 += bf2f(u.y); az0 += bf2f(u.z); aw0 += bf2f(u.w);
    }
    float dv = dinv[node];
    const float4* bv = (const float4*)bias;
    float4 bb = bv[lane];
    float4 o;
    o.x = (ax0 + ax1) * dv + bb.x; o.y = (ay0 + ay1) * dv + bb.y;
    o.z = (az0 + az1) * dv + bb.z; o.w = (aw0 + aw1) * dv + bb.w;
    ((float4*)out)[(size_t)node * 16 + lane] = o;
}

extern "C" void kernel_launch(void* const* d_in, const int* in_sizes, int n_in,
                              void* d_out, int out_size, void* d_ws, size_t ws_size,
                              hipStream_t stream) {
    const float* x   = (const float*)d_in[0];
    const int*   ei  = (const int*)d_in[1];
    const float* W1  = (const float*)d_in[2];
    const float* W2  = (const float*)d_in[4];
    const float* W3  = (const float*)d_in[6];
    const float* b3  = (const float*)d_in[7];
    const float* g1  = (const float*)d_in[8];
    const float* be1 = (const float*)d_in[9];
    const float* g2  = (const float*)d_in[10];
    const float* be2 = (const float*)d_in[11];
    float* out = (float*)d_out;

    const int N = in_sizes[0] / 128;
    const int E = in_sizes[1] / 2;
    const int* src = ei;
    const int* dst = ei + E;

    const int gG = (N + 7) / 8;              // gather blocks (6250)

    char* p = (char*)d_ws;
    float* dinv  = (float*)p;               p += (size_t)N * 4;
    unsigned short* xs = (unsigned short*)p; p += (size_t)N * 128 * 2;  // GEMM output (bf16)
    unsigned short* h1 = (unsigned short*)p; p += (size_t)N * 128 * 2;  // residual (bf16)
    float* agg   = (float*)p;               p += (size_t)N * 128 * 4;
    float* gsum  = (float*)p;               p += 128 * 4;
    float* gsq   = (float*)p;               p += 128 * 4;
    float* scratch = (float*)p;             p += (size_t)gG * 256 * 4;  // stat partials
    unsigned short* Wp1 = (unsigned short*)p; p += 16384 * 2;
    unsigned short* Wp2 = (unsigned short*)p; p += 16384 * 2;
    unsigned short* Wp3 = (unsigned short*)p; p += 8192 * 2;
    int*   ccnt  = (int*)p;                 p += 256 * 4;
    int*   cbase = (int*)p;                 p += 260 * 4;   // 257 used
    int*   ccur  = (int*)p;                 p += 256 * 4;
    unsigned int* pairs = (unsigned int*)p; p += (size_t)E * 4;
    int*   rs    = (int*)p;                 p += (size_t)(N + 16) * 4;
    int*   eb    = (int*)p;                 p += (size_t)E * 4;

    const int B = 256;
    const int gT    = (N + 63) / 64;
    const int gEchk = (E + 4095) / 4096;
    const int gN256 = (N + 255) / 256;
    const float inv_n = 1.0f / (float)N;

    // ---- CSR build (2-level counting sort) + weight packing ----
    hipMemsetAsync(ccnt, 0, 256 * 4, stream);
    k_hist_coarse<<<gEchk, B, 0, stream>>>(dst, ccnt, E);
    k_scan_coarse<<<1, B, 0, stream>>>(ccnt, cbase, ccur);
    k_partition<<<gEchk, B, 0, stream>>>(src, dst, ccur, pairs, E);
    k_fine<<<gN256, B, 0, stream>>>(pairs, cbase, rs, eb, dinv, N, E);
    k_packW_all<<<20, B, 0, stream>>>(W1, W2, W3, Wp1, Wp2, Wp3);

    // ---- layer 1: xs = (bf16(x)@W1)*dinv; agg = gather (+BN1 partials) ----
    k_gemm_mfma128_f32<<<gT, B, 0, stream>>>(x, Wp1, xs, dinv, N);
    k_gather128<<<gG, B, 0, stream>>>(agg, xs, rs, eb, dinv, scratch, N);
    k_colreduce<<<128, B, 0, stream>>>(scratch, gsum, gsq, gG);

    // ---- layer 2: h1=relu(bn(agg))+x fused in GEMM (bf16 side-write); gather (+BN2) ----
    k_gemm_mfma128_bn<<<gT, B, 0, stream>>>(agg, x, gsum, gsq, g1, be1, inv_n,
                                            h1, Wp2, xs, dinv, N);
    k_gather128<<<gG, B, 0, stream>>>(agg, xs, rs, eb, dinv, scratch, N);
    k_colreduce<<<128, B, 0, stream>>>(scratch, gsum, gsq, gG);

    // ---- layer 3: h2=relu(bn(agg))+h1(bf16) fused in GEMM; out = gather + b3 ----
    k_gemm_mfma64_bn<<<gT, B, 0, stream>>>(agg, h1, gsum, gsq, g2, be2, inv_n,
                                           Wp3, xs, dinv, N);
    k_gather64_bias<<<(N + 15) / 16, B, 0, stream>>>(out, xs, rs, eb, dinv, b3, N);
}